// Round 2
// baseline (3443.139 us; speedup 1.0000x reference)
//
#include <hip/hip_runtime.h>
#include <hip/hip_bf16.h>
#include <math.h>

#define N_ROWS 131072
#define DIN    768
#define DHID   512
#define DCODE  256
#define KCODES 512

// ---------------------------------------------------------------------------
// Tiled SGEMM: C[M,N] = act(A[M,K] @ B[K,N] + bias), row-major.
// BM=BN=128, BK=16, 256 threads, 8x8 per thread.
// NUMERICS: each C element is ONE fp32 fmaf chain over k ascending, acc=0,
// bias added as a separate rounded add in the epilogue — bitwise identical to
// a k-sequential FMA BLAS sgemm + numpy broadcast bias add.
// GATHER: A row index indirected through rowidx (codebook gather fused).
// ---------------------------------------------------------------------------
template<bool RELU, bool GATHER>
__global__ __launch_bounds__(256, 2)
void gemm_kernel(const float* __restrict__ A, const float* __restrict__ B,
                 const float* __restrict__ bias, const int* __restrict__ rowidx,
                 float* __restrict__ C, int M, int N, int K)
{
    __shared__ float As[16][128];   // As[k][m]
    __shared__ float Bs[16][128];   // Bs[k][n]
    const int t  = threadIdx.x;
    const int bm = blockIdx.y * 128;
    const int bn = blockIdx.x * 128;
    const int tx = t & 15;
    const int ty = t >> 4;

    float acc[8][8];
    #pragma unroll
    for (int i = 0; i < 8; i++)
        #pragma unroll
        for (int j = 0; j < 8; j++) acc[i][j] = 0.f;

    const int ar = t >> 2;          // 0..63
    const int ac = (t & 3) * 4;     // 0,4,8,12
    int arow0, arow1;
    if (GATHER) { arow0 = rowidx[bm + ar]; arow1 = rowidx[bm + ar + 64]; }
    else        { arow0 = bm + ar;         arow1 = bm + ar + 64; }
    const float* Arow0 = A + (size_t)arow0 * K + ac;
    const float* Arow1 = A + (size_t)arow1 * K + ac;
    const int br = t >> 4;
    const int bc = (t & 15) * 8;
    const float* Brow = B + (size_t)br * N + bn + bc;

    for (int k0 = 0; k0 < K; k0 += 16) {
        float4 a0 = *(const float4*)(Arow0 + k0);
        float4 a1 = *(const float4*)(Arow1 + k0);
        float4 b0 = *(const float4*)(Brow + (size_t)k0 * N);
        float4 b1 = *(const float4*)(Brow + (size_t)k0 * N + 4);
        __syncthreads();
        As[ac+0][ar] = a0.x; As[ac+1][ar] = a0.y; As[ac+2][ar] = a0.z; As[ac+3][ar] = a0.w;
        As[ac+0][ar+64] = a1.x; As[ac+1][ar+64] = a1.y; As[ac+2][ar+64] = a1.z; As[ac+3][ar+64] = a1.w;
        *(float4*)&Bs[br][bc]     = b0;
        *(float4*)&Bs[br][bc + 4] = b1;
        __syncthreads();
        #pragma unroll
        for (int kk = 0; kk < 16; kk++) {
            float4 A0 = *(const float4*)&As[kk][ty * 8];
            float4 A1 = *(const float4*)&As[kk][ty * 8 + 4];
            float4 B0 = *(const float4*)&Bs[kk][tx * 4];
            float4 B1 = *(const float4*)&Bs[kk][tx * 4 + 64];
            float av[8] = {A0.x,A0.y,A0.z,A0.w,A1.x,A1.y,A1.z,A1.w};
            float bv[8] = {B0.x,B0.y,B0.z,B0.w,B1.x,B1.y,B1.z,B1.w};
            #pragma unroll
            for (int i = 0; i < 8; i++)
                #pragma unroll
                for (int j = 0; j < 8; j++)
                    acc[i][j] = fmaf(av[i], bv[j], acc[i][j]);
        }
    }

    const int crow = bm + ty * 8;
    const int c0   = bn + tx * 4;
    float bs0[4], bs1[4];
    if (bias) {
        float4 bb0 = *(const float4*)(bias + c0);
        float4 bb1 = *(const float4*)(bias + c0 + 64);
        bs0[0]=bb0.x; bs0[1]=bb0.y; bs0[2]=bb0.z; bs0[3]=bb0.w;
        bs1[0]=bb1.x; bs1[1]=bb1.y; bs1[2]=bb1.z; bs1[3]=bb1.w;
    } else {
        bs0[0]=bs0[1]=bs0[2]=bs0[3]=0.f;
        bs1[0]=bs1[1]=bs1[2]=bs1[3]=0.f;
    }
    #pragma unroll
    for (int i = 0; i < 8; i++) {
        float4 o0, o1;
        float v;
        v = __fadd_rn(acc[i][0], bs0[0]); o0.x = RELU ? fmaxf(v, 0.f) : v;
        v = __fadd_rn(acc[i][1], bs0[1]); o0.y = RELU ? fmaxf(v, 0.f) : v;
        v = __fadd_rn(acc[i][2], bs0[2]); o0.z = RELU ? fmaxf(v, 0.f) : v;
        v = __fadd_rn(acc[i][3], bs0[3]); o0.w = RELU ? fmaxf(v, 0.f) : v;
        v = __fadd_rn(acc[i][4], bs1[0]); o1.x = RELU ? fmaxf(v, 0.f) : v;
        v = __fadd_rn(acc[i][5], bs1[1]); o1.y = RELU ? fmaxf(v, 0.f) : v;
        v = __fadd_rn(acc[i][6], bs1[2]); o1.z = RELU ? fmaxf(v, 0.f) : v;
        v = __fadd_rn(acc[i][7], bs1[3]); o1.w = RELU ? fmaxf(v, 0.f) : v;
        *(float4*)&C[(size_t)(crow + i) * N + c0]      = o0;
        *(float4*)&C[(size_t)(crow + i) * N + c0 + 64] = o1;
    }
}

// ---------------------------------------------------------------------------
__global__ void transpose_cb_kernel(const float* __restrict__ cb, float* __restrict__ cbT)
{
    int tid = blockIdx.x * 256 + threadIdx.x;   // 512*256 total
    int k = tid >> 8;
    int d = tid & 255;
    cbT[(size_t)d * KCODES + k] = cb[(size_t)k * DCODE + d];
}

// ---------------------------------------------------------------------------
// ||c_k||^2 replicating numpy float32 semantics bitwise:
// elementwise fp32 mul, then np.sum pairwise summation for n=256:
// two 128-blocks (each: 8 partial accumulators unrolled by 8, combined as
// ((r0+r1)+(r2+r3))+((r4+r5)+(r6+r7))), then block0+block1.
// ---------------------------------------------------------------------------
__global__ void cnorm_np_kernel(const float* __restrict__ cb, float* __restrict__ cnorm)
{
    int k = blockIdx.x * 64 + threadIdx.x;
    if (k >= KCODES) return;
    const float* c = cb + (size_t)k * DCODE;
    float bsum[2];
    #pragma unroll
    for (int b = 0; b < 2; b++) {
        const float* a = c + b * 128;
        float r[8];
        #pragma unroll
        for (int j = 0; j < 8; j++) r[j] = __fmul_rn(a[j], a[j]);
        for (int i = 8; i < 128; i += 8)
            #pragma unroll
            for (int j = 0; j < 8; j++)
                r[j] = __fadd_rn(r[j], __fmul_rn(a[i + j], a[i + j]));
        bsum[b] = __fadd_rn(
            __fadd_rn(__fadd_rn(r[0], r[1]), __fadd_rn(r[2], r[3])),
            __fadd_rn(__fadd_rn(r[4], r[5]), __fadd_rn(r[6], r[7])));
    }
    cnorm[k] = __fadd_rn(bsum[0], bsum[1]);
}

// ---------------------------------------------------------------------------
// Per-row argmin over 512 codes, pure fp32 mirroring the reference:
// dist[k] = cnorm[k] - 2.0f*dot[k]  (explicit non-contracted mul+sub),
// np.argmin tie-break = lowest index. One wave per row. Also emits
// rowloss = ||c_win - z||^2 (fp32; loss tolerance is lenient).
// ---------------------------------------------------------------------------
__global__ void argmin_kernel(const float* __restrict__ dots,
                              const float* __restrict__ z,
                              const float* __restrict__ cnorm,
                              const float* __restrict__ cb,
                              float* __restrict__ idx_f,
                              int* __restrict__ idx_i,
                              float* __restrict__ rowloss,
                              int nrows)
{
    int gw   = (blockIdx.x * blockDim.x + threadIdx.x) >> 6;
    int lane = threadIdx.x & 63;
    if (gw >= nrows) return;
    const float* dr = dots + (size_t)gw * KCODES;

    float d1 = INFINITY;
    int   i1 = 0x7fffffff;
    #pragma unroll
    for (int j = 0; j < KCODES / 64; j++) {
        int k = j * 64 + lane;
        float dist = __fsub_rn(cnorm[k], __fmul_rn(2.0f, dr[k]));
        if (dist < d1 || (dist == d1 && k < i1)) { d1 = dist; i1 = k; }
    }
    for (int off = 32; off; off >>= 1) {
        float od = __shfl_xor(d1, off);
        int   oi = __shfl_xor(i1, off);
        if (od < d1 || (od == d1 && oi < i1)) { d1 = od; i1 = oi; }
    }

    const float* zr = z + (size_t)gw * DCODE;
    const float* cr = cb + (size_t)i1 * DCODE;
    float4 zv = *(const float4*)(zr + lane * 4);
    float4 cv = *(const float4*)(cr + lane * 4);
    float ex = cv.x - zv.x, ey = cv.y - zv.y, ez = cv.z - zv.z, ew = cv.w - zv.w;
    float s = ex*ex + ey*ey + ez*ez + ew*ew;
    for (int off = 32; off; off >>= 1) s += __shfl_xor(s, off);

    if (lane == 0) {
        idx_f[gw]   = (float)i1;
        idx_i[gw]   = i1;
        rowloss[gw] = s;
    }
}

// ---------------------------------------------------------------------------
__global__ void loss_reduce_kernel(const float* __restrict__ rowloss,
                                   double* __restrict__ acc, int n)
{
    double s = 0.0;
    for (int i = blockIdx.x * blockDim.x + threadIdx.x; i < n; i += gridDim.x * blockDim.x)
        s += (double)rowloss[i];
    for (int off = 32; off; off >>= 1) s += __shfl_xor(s, off);
    __shared__ double red[4];
    int lane = threadIdx.x & 63, wave = threadIdx.x >> 6;
    if (lane == 0) red[wave] = s;
    __syncthreads();
    if (threadIdx.x == 0) {
        double b = red[0] + red[1] + red[2] + red[3];
        atomicAdd(acc, b);
    }
}

__global__ void finalize_kernel(const double* __restrict__ acc, float* __restrict__ out)
{
    out[0] = (float)(acc[0] / ((double)N_ROWS * (double)DCODE));
}

// ---------------------------------------------------------------------------
extern "C" void kernel_launch(void* const* d_in, const int* in_sizes, int n_in,
                              void* d_out, int out_size, void* d_ws, size_t ws_size,
                              hipStream_t stream)
{
    const float* x  = (const float*)d_in[0];
    const float* W1 = (const float*)d_in[1];
    const float* b1 = (const float*)d_in[2];
    const float* W2 = (const float*)d_in[3];
    const float* b2 = (const float*)d_in[4];
    const float* cb = (const float*)d_in[5];
    const float* W3 = (const float*)d_in[6];
    const float* b3 = (const float*)d_in[7];
    const float* W4 = (const float*)d_in[8];
    const float* b4 = (const float*)d_in[9];
    float* out = (float*)d_out;
    char*  ws  = (char*)d_ws;

    // ws layout (bytes)
    float*  buf0    = (float*) (ws);                      // 268435456: h1 / dots / h2
    float*  zbuf    = (float*) (ws + 268435456);          // 134217728
    float*  cbT     = (float*) (ws + 402653184);          // 524288
    float*  cnorm   = (float*) (ws + 403177472);          // 2048
    int*    idxi    = (int*)   (ws + 403181568);          // 524288
    float*  rowloss = (float*) (ws + 403705856);          // 524288
    double* lossa   = (double*)(ws + 404230144);          // 8

    float* idxf    = out + (size_t)N_ROWS * DIN;          // indices as float
    float* lossout = idxf + N_ROWS;                       // scalar loss

    hipMemsetAsync(ws + 404230144, 0, 8, stream);         // lossa

    transpose_cb_kernel<<<512, 256, 0, stream>>>(cb, cbT);
    cnorm_np_kernel<<<8, 64, 0, stream>>>(cb, cnorm);

    // encoder (bitwise fp32 k-sequential FMA chains)
    gemm_kernel<true,  false><<<dim3(DHID/128,  N_ROWS/128), 256, 0, stream>>>(
        x, W1, b1, nullptr, buf0, N_ROWS, DHID, DIN);                  // h1
    gemm_kernel<false, false><<<dim3(DCODE/128, N_ROWS/128), 256, 0, stream>>>(
        buf0, W2, b2, nullptr, zbuf, N_ROWS, DCODE, DHID);             // z
    gemm_kernel<false, false><<<dim3(KCODES/128, N_ROWS/128), 256, 0, stream>>>(
        zbuf, cbT, nullptr, nullptr, buf0, N_ROWS, KCODES, DCODE);     // dots

    argmin_kernel<<<N_ROWS/4, 256, 0, stream>>>(buf0, zbuf, cnorm, cb,
        idxf, idxi, rowloss, N_ROWS);

    // decoder (quantized_st == codebook[idx] numerically; gather fused)
    gemm_kernel<true,  true ><<<dim3(DHID/128, N_ROWS/128), 256, 0, stream>>>(
        cb, W3, b3, idxi, buf0, N_ROWS, DHID, DCODE);                  // h2
    gemm_kernel<false, false><<<dim3(DIN/128,  N_ROWS/128), 256, 0, stream>>>(
        buf0, W4, b4, nullptr, out, N_ROWS, DIN, DHID);                // recon

    loss_reduce_kernel<<<256, 256, 0, stream>>>(rowloss, lossa, N_ROWS);
    finalize_kernel<<<1, 1, 0, stream>>>(lossa, lossout);
}

// Round 3
// 2250.378 us; speedup vs baseline: 1.5300x; 1.5300x over previous
//
#include <hip/hip_runtime.h>
#include <hip/hip_bf16.h>
#include <math.h>

#define N_ROWS 131072
#define DIN    768
#define DHID   512
#define DCODE  256
#define KCODES 512

typedef short short8 __attribute__((ext_vector_type(8)));
typedef float f32x4  __attribute__((ext_vector_type(4)));
typedef unsigned int   u32;
typedef unsigned short u16;

__device__ __forceinline__ void gload16(const void* g, void* l) {
    __builtin_amdgcn_global_load_lds(
        (const __attribute__((address_space(1))) u32*)g,
        (__attribute__((address_space(3))) u32*)l, 16, 0, 0);
}

__device__ __forceinline__ u16 f2bf(float f) {
    u32 u = __builtin_bit_cast(u32, f);
    return (u16)((u + 0x7fffu + ((u >> 16) & 1u)) >> 16);
}

// ---------------------------------------------------------------------------
// fp32 tiled SGEMM — BITWISE path (h1, z, dots). Each C element is one fp32
// fmaf chain over k ascending from 0; bias added as separate rounded add.
// LDS padded to stride 132 (bank-conflict fix; pure address change).
// ---------------------------------------------------------------------------
template<bool RELU, bool GATHER>
__global__ __launch_bounds__(256, 2)
void gemm_kernel(const float* __restrict__ A, const float* __restrict__ B,
                 const float* __restrict__ bias, const int* __restrict__ rowidx,
                 float* __restrict__ C, int M, int N, int K)
{
    __shared__ float As[16][132];
    __shared__ float Bs[16][132];
    const int t  = threadIdx.x;
    const int bm = blockIdx.y * 128;
    const int bn = blockIdx.x * 128;
    const int tx = t & 15;
    const int ty = t >> 4;

    float acc[8][8];
    #pragma unroll
    for (int i = 0; i < 8; i++)
        #pragma unroll
        for (int j = 0; j < 8; j++) acc[i][j] = 0.f;

    const int ar = t >> 2;
    const int ac = (t & 3) * 4;
    int arow0, arow1;
    if (GATHER) { arow0 = rowidx[bm + ar]; arow1 = rowidx[bm + ar + 64]; }
    else        { arow0 = bm + ar;         arow1 = bm + ar + 64; }
    const float* Arow0 = A + (size_t)arow0 * K + ac;
    const float* Arow1 = A + (size_t)arow1 * K + ac;
    const int br = t >> 4;
    const int bc = (t & 15) * 8;
    const float* Brow = B + (size_t)br * N + bn + bc;

    for (int k0 = 0; k0 < K; k0 += 16) {
        float4 a0 = *(const float4*)(Arow0 + k0);
        float4 a1 = *(const float4*)(Arow1 + k0);
        float4 b0 = *(const float4*)(Brow + (size_t)k0 * N);
        float4 b1 = *(const float4*)(Brow + (size_t)k0 * N + 4);
        __syncthreads();
        As[ac+0][ar] = a0.x; As[ac+1][ar] = a0.y; As[ac+2][ar] = a0.z; As[ac+3][ar] = a0.w;
        As[ac+0][ar+64] = a1.x; As[ac+1][ar+64] = a1.y; As[ac+2][ar+64] = a1.z; As[ac+3][ar+64] = a1.w;
        *(float4*)&Bs[br][bc]     = b0;
        *(float4*)&Bs[br][bc + 4] = b1;
        __syncthreads();
        #pragma unroll
        for (int kk = 0; kk < 16; kk++) {
            float4 A0 = *(const float4*)&As[kk][ty * 8];
            float4 A1 = *(const float4*)&As[kk][ty * 8 + 4];
            float4 B0 = *(const float4*)&Bs[kk][tx * 4];
            float4 B1 = *(const float4*)&Bs[kk][tx * 4 + 64];
            float av[8] = {A0.x,A0.y,A0.z,A0.w,A1.x,A1.y,A1.z,A1.w};
            float bv[8] = {B0.x,B0.y,B0.z,B0.w,B1.x,B1.y,B1.z,B1.w};
            #pragma unroll
            for (int i = 0; i < 8; i++)
                #pragma unroll
                for (int j = 0; j < 8; j++)
                    acc[i][j] = fmaf(av[i], bv[j], acc[i][j]);
        }
    }

    const int crow = bm + ty * 8;
    const int c0   = bn + tx * 4;
    float bs0[4], bs1[4];
    if (bias) {
        float4 bb0 = *(const float4*)(bias + c0);
        float4 bb1 = *(const float4*)(bias + c0 + 64);
        bs0[0]=bb0.x; bs0[1]=bb0.y; bs0[2]=bb0.z; bs0[3]=bb0.w;
        bs1[0]=bb1.x; bs1[1]=bb1.y; bs1[2]=bb1.z; bs1[3]=bb1.w;
    } else {
        bs0[0]=bs0[1]=bs0[2]=bs0[3]=0.f;
        bs1[0]=bs1[1]=bs1[2]=bs1[3]=0.f;
    }
    #pragma unroll
    for (int i = 0; i < 8; i++) {
        float4 o0, o1;
        float v;
        v = __fadd_rn(acc[i][0], bs0[0]); o0.x = RELU ? fmaxf(v, 0.f) : v;
        v = __fadd_rn(acc[i][1], bs0[1]); o0.y = RELU ? fmaxf(v, 0.f) : v;
        v = __fadd_rn(acc[i][2], bs0[2]); o0.z = RELU ? fmaxf(v, 0.f) : v;
        v = __fadd_rn(acc[i][3], bs0[3]); o0.w = RELU ? fmaxf(v, 0.f) : v;
        v = __fadd_rn(acc[i][4], bs1[0]); o1.x = RELU ? fmaxf(v, 0.f) : v;
        v = __fadd_rn(acc[i][5], bs1[1]); o1.y = RELU ? fmaxf(v, 0.f) : v;
        v = __fadd_rn(acc[i][6], bs1[2]); o1.z = RELU ? fmaxf(v, 0.f) : v;
        v = __fadd_rn(acc[i][7], bs1[3]); o1.w = RELU ? fmaxf(v, 0.f) : v;
        *(float4*)&C[(size_t)(crow + i) * N + c0]      = o0;
        *(float4*)&C[(size_t)(crow + i) * N + c0 + 64] = o1;
    }
}

// ---------------------------------------------------------------------------
// bf16 MFMA GEMM (decoder only; lenient tolerance).
// C[M,N] = act(A[M,K] @ BT[N,K]^T + bias). A,BT bf16 row-major (BT = B^T).
// 128x128 tile, BK=64, 4 waves (2x2), 16x16x32 MFMA, global_load_lds(16B)
// with pre-swizzled source cols; XOR-swizzled ds_read_b128; LDS double-buffer,
// 1 barrier-pair per K-tile with next-tile prefetch in flight (T3 minimum).
// ---------------------------------------------------------------------------
template<bool RELU, bool GATHER, bool OUT_BF16>
__global__ __launch_bounds__(256, 2)
void mfma_gemm(const u16* __restrict__ A, const u16* __restrict__ BT,
               const float* __restrict__ bias, const int* __restrict__ rowidx,
               void* __restrict__ Cout, int M, int N, int K)
{
    __shared__ char lds[65536];   // buf c: A at c*32768, B at c*32768+16384
    const int t    = threadIdx.x;
    const int lane = t & 63, wid = t >> 6;
    const int wm   = wid >> 1, wn = wid & 1;
    const int bm   = blockIdx.y * 128, bn = blockIdx.x * 128;

    // staging: chunk = 8 rows x 64 bf16; lane -> row sr, src col pre-swizzled
    const int sr = lane >> 3;
    const int sc = ((lane & 7) ^ sr) * 8;       // inverse-swizzled source col
    const u16* aptr[4];
    const u16* bptr[4];
    #pragma unroll
    for (int c = 0; c < 4; c++) {
        int gc   = wid * 4 + c;
        int arow = bm + 8 * gc + sr;
        if (GATHER) arow = rowidx[arow];
        aptr[c] = A  + (size_t)arow * K + sc;
        int brow = bn + 8 * gc + sr;
        bptr[c] = BT + (size_t)brow * K + sc;
    }

    f32x4 acc[4][4];
    #pragma unroll
    for (int i = 0; i < 4; i++)
        #pragma unroll
        for (int j = 0; j < 4; j++) acc[i][j] = (f32x4)0.f;

    // frag-read byte offsets (swizzled): k-slot ^ ((row&7)<<4), row&7 == lane&7
    const int koff0 = (16 * (lane >> 4))      ^ ((lane & 7) << 4);
    const int koff1 = (64 + 16 * (lane >> 4)) ^ ((lane & 7) << 4);
    const int arow_rd = wm * 64 + (lane & 15);
    const int brow_rd = wn * 64 + (lane & 15);

    const int NT = K >> 6;
    // prologue: stage tile 0 into buf 0
    #pragma unroll
    for (int c = 0; c < 4; c++) {
        int gc = wid * 4 + c;
        gload16(aptr[c], lds + gc * 1024);
        gload16(bptr[c], lds + 16384 + gc * 1024);
    }
    __syncthreads();

    int cur = 0;
    for (int tt = 0; tt < NT; tt++) {
        if (tt + 1 < NT) {
            const int k0 = (tt + 1) << 6;
            char* nb = lds + (cur ^ 1) * 32768;
            #pragma unroll
            for (int c = 0; c < 4; c++) {
                int gc = wid * 4 + c;
                gload16(aptr[c] + k0, nb + gc * 1024);
                gload16(bptr[c] + k0, nb + 16384 + gc * 1024);
            }
        }
        char* ldsA = lds + cur * 32768;
        char* ldsB = ldsA + 16384;
        #pragma unroll
        for (int kk = 0; kk < 2; kk++) {
            const int ko = kk ? koff1 : koff0;
            short8 af[4], bfr[4];
            #pragma unroll
            for (int i = 0; i < 4; i++)
                af[i]  = *(const short8*)(ldsA + (arow_rd + i * 16) * 128 + ko);
            #pragma unroll
            for (int j = 0; j < 4; j++)
                bfr[j] = *(const short8*)(ldsB + (brow_rd + j * 16) * 128 + ko);
            #pragma unroll
            for (int i = 0; i < 4; i++)
                #pragma unroll
                for (int j = 0; j < 4; j++)
                    acc[i][j] = __builtin_amdgcn_mfma_f32_16x16x32_bf16(
                        af[i], bfr[j], acc[i][j], 0, 0, 0);
        }
        __syncthreads();   // drains vmcnt(0): next tile staged; reads done
        cur ^= 1;
    }

    const int er = (lane >> 4) * 4;
    const int ec = lane & 15;
    #pragma unroll
    for (int j = 0; j < 4; j++) {
        int col  = bn + wn * 64 + j * 16 + ec;
        float bb = bias[col];
        #pragma unroll
        for (int i = 0; i < 4; i++) {
            #pragma unroll
            for (int e = 0; e < 4; e++) {
                int r   = bm + wm * 64 + i * 16 + er + e;
                float v = acc[i][j][e] + bb;
                if (RELU) v = fmaxf(v, 0.f);
                if (OUT_BF16) ((u16*)Cout)[(size_t)r * N + col]  = f2bf(v);
                else          ((float*)Cout)[(size_t)r * N + col] = v;
            }
        }
    }
}

// ---------------------------------------------------------------------------
__global__ void transpose_cb_kernel(const float* __restrict__ cb, float* __restrict__ cbT)
{
    int tid = blockIdx.x * 256 + threadIdx.x;
    int k = tid >> 8;
    int d = tid & 255;
    cbT[(size_t)d * KCODES + k] = cb[(size_t)k * DCODE + d];
}

__global__ void cast_bf16_kernel(const float* __restrict__ in, u16* __restrict__ out, int n)
{
    int i = blockIdx.x * 256 + threadIdx.x;
    if (i < n) out[i] = f2bf(in[i]);
}

// in [K][N] fp32 -> out [N][K] bf16
__global__ void castT_bf16_kernel(const float* __restrict__ in, u16* __restrict__ out,
                                  int K, int N)
{
    int i = blockIdx.x * 256 + threadIdx.x;
    if (i >= K * N) return;
    int n = i / K, k = i - n * K;
    out[i] = f2bf(in[(size_t)k * N + n]);
}

// ---------------------------------------------------------------------------
// ||c_k||^2 replicating numpy float32 pairwise-summation bitwise.
// ---------------------------------------------------------------------------
__global__ void cnorm_np_kernel(const float* __restrict__ cb, float* __restrict__ cnorm)
{
    int k = blockIdx.x * 64 + threadIdx.x;
    if (k >= KCODES) return;
    const float* c = cb + (size_t)k * DCODE;
    float bsum[2];
    #pragma unroll
    for (int b = 0; b < 2; b++) {
        const float* a = c + b * 128;
        float r[8];
        #pragma unroll
        for (int j = 0; j < 8; j++) r[j] = __fmul_rn(a[j], a[j]);
        for (int i = 8; i < 128; i += 8)
            #pragma unroll
            for (int j = 0; j < 8; j++)
                r[j] = __fadd_rn(r[j], __fmul_rn(a[i + j], a[i + j]));
        bsum[b] = __fadd_rn(
            __fadd_rn(__fadd_rn(r[0], r[1]), __fadd_rn(r[2], r[3])),
            __fadd_rn(__fadd_rn(r[4], r[5]), __fadd_rn(r[6], r[7])));
    }
    cnorm[k] = __fadd_rn(bsum[0], bsum[1]);
}

// ---------------------------------------------------------------------------
__global__ void argmin_kernel(const float* __restrict__ dots,
                              const float* __restrict__ z,
                              const float* __restrict__ cnorm,
                              const float* __restrict__ cb,
                              float* __restrict__ idx_f,
                              int* __restrict__ idx_i,
                              float* __restrict__ rowloss,
                              int nrows)
{
    int gw   = (blockIdx.x * blockDim.x + threadIdx.x) >> 6;
    int lane = threadIdx.x & 63;
    if (gw >= nrows) return;
    const float* dr = dots + (size_t)gw * KCODES;

    float d1 = INFINITY;
    int   i1 = 0x7fffffff;
    #pragma unroll
    for (int j = 0; j < KCODES / 64; j++) {
        int k = j * 64 + lane;
        float dist = __fsub_rn(cnorm[k], __fmul_rn(2.0f, dr[k]));
        if (dist < d1 || (dist == d1 && k < i1)) { d1 = dist; i1 = k; }
    }
    for (int off = 32; off; off >>= 1) {
        float od = __shfl_xor(d1, off);
        int   oi = __shfl_xor(i1, off);
        if (od < d1 || (od == d1 && oi < i1)) { d1 = od; i1 = oi; }
    }

    const float* zr = z + (size_t)gw * DCODE;
    const float* cr = cb + (size_t)i1 * DCODE;
    float4 zv = *(const float4*)(zr + lane * 4);
    float4 cv = *(const float4*)(cr + lane * 4);
    float ex = cv.x - zv.x, ey = cv.y - zv.y, ez = cv.z - zv.z, ew = cv.w - zv.w;
    float s = ex*ex + ey*ey + ez*ez + ew*ew;
    for (int off = 32; off; off >>= 1) s += __shfl_xor(s, off);

    if (lane == 0) {
        idx_f[gw]   = (float)i1;
        idx_i[gw]   = i1;
        rowloss[gw] = s;
    }
}

// ---------------------------------------------------------------------------
__global__ void loss_reduce_kernel(const float* __restrict__ rowloss,
                                   double* __restrict__ acc, int n)
{
    double s = 0.0;
    for (int i = blockIdx.x * blockDim.x + threadIdx.x; i < n; i += gridDim.x * blockDim.x)
        s += (double)rowloss[i];
    for (int off = 32; off; off >>= 1) s += __shfl_xor(s, off);
    __shared__ double red[4];
    int lane = threadIdx.x & 63, wave = threadIdx.x >> 6;
    if (lane == 0) red[wave] = s;
    __syncthreads();
    if (threadIdx.x == 0) {
        double b = red[0] + red[1] + red[2] + red[3];
        atomicAdd(acc, b);
    }
}

__global__ void finalize_kernel(const double* __restrict__ acc, float* __restrict__ out)
{
    out[0] = (float)(acc[0] / ((double)N_ROWS * (double)DCODE));
}

// ---------------------------------------------------------------------------
extern "C" void kernel_launch(void* const* d_in, const int* in_sizes, int n_in,
                              void* d_out, int out_size, void* d_ws, size_t ws_size,
                              hipStream_t stream)
{
    const float* x  = (const float*)d_in[0];
    const float* W1 = (const float*)d_in[1];
    const float* b1 = (const float*)d_in[2];
    const float* W2 = (const float*)d_in[3];
    const float* b2 = (const float*)d_in[4];
    const float* cb = (const float*)d_in[5];
    const float* W3 = (const float*)d_in[6];
    const float* b3 = (const float*)d_in[7];
    const float* W4 = (const float*)d_in[8];
    const float* b4 = (const float*)d_in[9];
    float* out = (float*)d_out;
    char*  ws  = (char*)d_ws;

    float*  buf0    = (float*) (ws);                      // 256 MB: h1, then dots
    float*  zbuf    = (float*) (ws + 268435456);          // 128 MB: z
    u16*    h2b     = (u16*)   (ws + 268435456);          // alias: h2 bf16 (z dead)
    float*  cbT     = (float*) (ws + 402653184);          // 512 KB
    float*  cnorm   = (float*) (ws + 403177472);          // 2 KB
    int*    idxi    = (int*)   (ws + 403181568);          // 512 KB
    float*  rowloss = (float*) (ws + 403705856);          // 512 KB
    double* lossa   = (double*)(ws + 404230144);          // 8 B
    u16*    cbB     = (u16*)   (ws + 404230208);          // 256 KB
    u16*    W3T     = (u16*)   (ws + 404492352);          // 256 KB
    u16*    W4T     = (u16*)   (ws + 404754496);          // 768 KB (ends ~405.5 MB)

    float* idxf    = out + (size_t)N_ROWS * DIN;
    float* lossout = idxf + N_ROWS;

    hipMemsetAsync(ws + 404230144, 0, 8, stream);

    transpose_cb_kernel<<<512, 256, 0, stream>>>(cb, cbT);
    cnorm_np_kernel<<<8, 64, 0, stream>>>(cb, cnorm);
    cast_bf16_kernel<<<(KCODES*DCODE)/256, 256, 0, stream>>>(cb, cbB, KCODES*DCODE);
    castT_bf16_kernel<<<(DCODE*DHID)/256, 256, 0, stream>>>(W3, W3T, DCODE, DHID);
    castT_bf16_kernel<<<(DHID*DIN)/256, 256, 0, stream>>>(W4, W4T, DHID, DIN);

    // encoder (bitwise fp32 chains)
    gemm_kernel<true,  false><<<dim3(DHID/128,  N_ROWS/128), 256, 0, stream>>>(
        x, W1, b1, nullptr, buf0, N_ROWS, DHID, DIN);                  // h1
    gemm_kernel<false, false><<<dim3(DCODE/128, N_ROWS/128), 256, 0, stream>>>(
        buf0, W2, b2, nullptr, zbuf, N_ROWS, DCODE, DHID);             // z
    gemm_kernel<false, false><<<dim3(KCODES/128, N_ROWS/128), 256, 0, stream>>>(
        zbuf, cbT, nullptr, nullptr, buf0, N_ROWS, KCODES, DCODE);     // dots

    argmin_kernel<<<N_ROWS/4, 256, 0, stream>>>(buf0, zbuf, cnorm, cb,
        idxf, idxi, rowloss, N_ROWS);

    // decoder (bf16 MFMA; z buffer now dead -> h2b aliases it)
    mfma_gemm<true,  true,  true ><<<dim3(DHID/128, N_ROWS/128), 256, 0, stream>>>(
        cbB, W3T, b3, idxi, (void*)h2b, N_ROWS, DHID, DCODE);          // h2 (bf16)
    mfma_gemm<false, false, false><<<dim3(DIN/128,  N_ROWS/128), 256, 0, stream>>>(
        h2b, W4T, b4, nullptr, (void*)out, N_ROWS, DIN, DHID);         // recon (f32)

    loss_reduce_kernel<<<256, 256, 0, stream>>>(rowloss, lossa, N_ROWS);
    finalize_kernel<<<1, 1, 0, stream>>>(lossa, lossout);
}